// Round 8
// baseline (306.811 us; speedup 1.0000x reference)
//
#include <hip/hip_runtime.h>

#define CD 1024
#define NB 4096

typedef __attribute__((ext_vector_type(8))) short short8;
typedef __attribute__((ext_vector_type(4))) short short4v;
typedef __attribute__((ext_vector_type(4))) float f32x4;
typedef __attribute__((ext_vector_type(4))) int int4v;

typedef __attribute__((address_space(1))) const void gv_t;
typedef __attribute__((address_space(3))) void lv_t;
#define GLOAD16(g, l) __builtin_amdgcn_global_load_lds((gv_t*)(g), (lv_t*)(l), 16, 0, 0)

__device__ __forceinline__ short f2bf(float f) {
  unsigned u = __float_as_uint(f);
  u = (u + 0x7FFFu + ((u >> 16) & 1u)) >> 16;
  return (short)u;
}
__device__ __forceinline__ float bf2f(short s) {
  return __uint_as_float(((unsigned)(unsigned short)s) << 16);
}

// ---- fused: x f32->bf16 (blocks 0..2047) + dequant12+LoRA-fold (blocks 2048..8191) ----
__global__ __launch_bounds__(256) void prep_kernel(const float* __restrict__ x,
                                                   short* __restrict__ xb,
                                                   const int* __restrict__ q4,
                                                   const float* __restrict__ nrm,
                                                   const float* __restrict__ la,
                                                   const float* __restrict__ lb,
                                                   short* __restrict__ Wb) {
  int bid = blockIdx.x;
  if (bid < 2048) {
    int i = (bid * 256 + threadIdx.x) * 8;
    f32x4 a = *(const f32x4*)(x + i);
    f32x4 b = *(const f32x4*)(x + i + 4);
    short8 o;
    o[0] = f2bf(a[0]); o[1] = f2bf(a[1]); o[2] = f2bf(a[2]); o[3] = f2bf(a[3]);
    o[4] = f2bf(b[0]); o[5] = f2bf(b[1]); o[6] = f2bf(b[2]); o[7] = f2bf(b[3]);
    *(short8*)(xb + i) = o;
    return;
  }
  int tidg = (bid - 2048) * 256 + threadIdx.x;
  int w0 = tidg * 4;
  int l = w0 >> 19;
  int wl = w0 & 524287;
  int g = wl >> 6;
  int j0 = wl & 63;
  int o = g >> 3;
  int kb = ((g & 7) << 7) + (j0 << 1);
  int4v q = *(const int4v*)(q4 + w0);
  float n = nrm[(l << 13) + g];
  float s = n * (2.0f / 15.0f);
  f32x4 B = *(const f32x4*)(lb + (((l << 10) + o) << 2));
  const float* A = la + (l << 12);
  float Ar[4][8];
#pragma unroll
  for (int r = 0; r < 4; ++r) {
    f32x4 u = *(const f32x4*)(A + r * CD + kb);
    f32x4 v = *(const f32x4*)(A + r * CD + kb + 4);
    Ar[r][0] = u[0]; Ar[r][1] = u[1]; Ar[r][2] = u[2]; Ar[r][3] = u[3];
    Ar[r][4] = v[0]; Ar[r][5] = v[1]; Ar[r][6] = v[2]; Ar[r][7] = v[3];
  }
  short8 outv;
#pragma unroll
  for (int p = 0; p < 8; ++p) {
    int qw = q[p >> 1];
    int nib = (qw >> ((p & 1) << 2)) & 15;
    float wv = (float)nib * s - n;
    wv += B[0] * Ar[0][p] + B[1] * Ar[1][p] + B[2] * Ar[2][p] + B[3] * Ar[3][p];
    outv[p] = f2bf(wv);
  }
  *(short8*)(Wb + (l << 20) + (o << 10) + kb) = outv;
}

// ---- GEMM: out[M,O] = Act[M,K] @ W[O,K]^T, bf16 in, f32 acc ----
// BM=BN=128, BK=64; 1024 thr = 16 waves = 4 waves/SIMD (occupancy probe).
// Wave-tile 32x32 (4x4 wave grid). LDS 64 KB dbuf, 2-phase schedule,
// grid 256 = 1 block/CU, XCD 4x8 patch map. Same verified swizzle/mappings.
// EPI: 0 = relu->bf16, 2 = +resid->bf16, 3 = +resid->f32
template <int EPI>
__global__ __launch_bounds__(1024, 4) void qgemm(const short* __restrict__ Act,
                                                 const short* __restrict__ W,
                                                 const short* __restrict__ Res,
                                                 void* __restrict__ Out) {
  __shared__ __align__(16) short ldsA[2][128 * 64];
  __shared__ __align__(16) short ldsB[2][128 * 64];
  const int tid = threadIdx.x;
  const int lane = tid & 63;
  const int wid = tid >> 6;
  const int wr = wid >> 2;                 // 0..3 : 32-row slice
  const int wc = wid & 3;                  // 0..3 : 32-col slice
  const int f = blockIdx.x;
  const int xcd = f & 7, c = f >> 3;
  const int m0 = (((xcd << 2) | (c & 3)) << 7);  // 32 M-tiles
  const int o0 = ((c >> 2) << 7);                // 8 O-tiles

  // staging: 1024 chunks of 16B per operand per buf; thread t stages chunk t.
  // Source pre-swizzled ch ^= row&7; LDS dest linear.
  const int srow = tid >> 3;               // 0..127
  const int sch = (tid & 7) ^ (srow & 7);
  const short* asrc = Act + (long)(m0 + srow) * CD + (sch << 3);
  const short* bsrc = W + (long)(o0 + srow) * CD + (sch << 3);

  auto stage = [&](int t, int buf) {
    const int koff = t << 6;
    GLOAD16(asrc + koff, &ldsA[buf][tid << 3]);
    GLOAD16(bsrc + koff, &ldsB[buf][tid << 3]);
  };

  f32x4 acc[2][2] = {};
  const int frow = lane & 15;
  const int fch = lane >> 4;               // 0..3
  const int fsw = lane & 7;

  stage(0, 0);
  for (int t = 0; t < 16; ++t) {
    __syncthreads();                       // buf[t&1] staged (drains vmcnt)
    if (t < 15) stage(t + 1, (t + 1) & 1);
    const short* La = ldsA[t & 1];
    const short* Lb = ldsB[t & 1];
#pragma unroll
    for (int kk = 0; kk < 2; ++kk) {
      const int chsw = ((kk << 2) + fch) ^ fsw;
      short8 af[2], wf[2];
#pragma unroll
      for (int m = 0; m < 2; ++m) {
        int row = (wr << 5) + (m << 4) + frow;
        af[m] = *(const short8*)(La + (row << 6) + (chsw << 3));
      }
#pragma unroll
      for (int n = 0; n < 2; ++n) {
        int row = (wc << 5) + (n << 4) + frow;
        wf[n] = *(const short8*)(Lb + (row << 6) + (chsw << 3));
      }
#pragma unroll
      for (int m = 0; m < 2; ++m)
#pragma unroll
        for (int n = 0; n < 2; ++n)
          acc[m][n] = __builtin_amdgcn_mfma_f32_16x16x32_bf16(wf[n], af[m], acc[m][n], 0, 0, 0);
    }
  }

  // epilogue (swapped operands): lane&15 = M-row, (lane>>4)*4+reg = out-col
  const int orow = m0 + (wr << 5) + frow;
  const int ocol = o0 + (wc << 5) + (fch << 2);
#pragma unroll
  for (int m = 0; m < 2; ++m) {
#pragma unroll
    for (int n = 0; n < 2; ++n) {
      long row = orow + (m << 4);
      int col = ocol + (n << 4);
      f32x4 v = acc[m][n];
      if (EPI == 0) {
        short4v ov;
        ov[0] = f2bf(fmaxf(v[0], 0.0f));
        ov[1] = f2bf(fmaxf(v[1], 0.0f));
        ov[2] = f2bf(fmaxf(v[2], 0.0f));
        ov[3] = f2bf(fmaxf(v[3], 0.0f));
        *(short4v*)((short*)Out + row * CD + col) = ov;
      } else if (EPI == 2) {
        short4v rv = *(const short4v*)(Res + row * CD + col);
        short4v ov;
        ov[0] = f2bf(v[0] + bf2f(rv[0]));
        ov[1] = f2bf(v[1] + bf2f(rv[1]));
        ov[2] = f2bf(v[2] + bf2f(rv[2]));
        ov[3] = f2bf(v[3] + bf2f(rv[3]));
        *(short4v*)((short*)Out + row * CD + col) = ov;
      } else {
        short4v rv = *(const short4v*)(Res + row * CD + col);
        f32x4 ov;
        ov[0] = v[0] + bf2f(rv[0]);
        ov[1] = v[1] + bf2f(rv[1]);
        ov[2] = v[2] + bf2f(rv[2]);
        ov[3] = v[3] + bf2f(rv[3]);
        *(f32x4*)((float*)Out + row * CD + col) = ov;
      }
    }
  }
}

// ---- LayerNorm over rows of 1024 bf16 ----
__global__ __launch_bounds__(256) void ln_kernel(const short* __restrict__ in,
                                                 short* __restrict__ out,
                                                 const float* __restrict__ g,
                                                 const float* __restrict__ b) {
  __shared__ float rs_[4], rq_[4];
  int row = blockIdx.x, tid = threadIdx.x;
  int k = tid * 4;
  short4v v = *(const short4v*)(in + (long)row * CD + k);
  float f0 = bf2f(v[0]), f1 = bf2f(v[1]), f2 = bf2f(v[2]), f3 = bf2f(v[3]);
  float s = f0 + f1 + f2 + f3;
  float q = f0 * f0 + f1 * f1 + f2 * f2 + f3 * f3;
#pragma unroll
  for (int off = 1; off < 64; off <<= 1) {
    s += __shfl_xor(s, off);
    q += __shfl_xor(q, off);
  }
  if ((tid & 63) == 0) { rs_[tid >> 6] = s; rq_[tid >> 6] = q; }
  __syncthreads();
  s = rs_[0] + rs_[1] + rs_[2] + rs_[3];
  q = rq_[0] + rq_[1] + rq_[2] + rq_[3];
  float mu = s * (1.0f / 1024.0f);
  float var = q * (1.0f / 1024.0f) - mu * mu;
  float rstd = rsqrtf(var + 1e-5f);
  short4v o;
  o[0] = f2bf((f0 - mu) * rstd * g[k] + b[k]);
  o[1] = f2bf((f1 - mu) * rstd * g[k + 1] + b[k + 1]);
  o[2] = f2bf((f2 - mu) * rstd * g[k + 2] + b[k + 2]);
  o[3] = f2bf((f3 - mu) * rstd * g[k + 3] + b[k + 3]);
  *(short4v*)(out + (long)row * CD + k) = o;
}

extern "C" void kernel_launch(void* const* d_in, const int* in_sizes, int n_in,
                              void* d_out, int out_size, void* d_ws, size_t ws_size,
                              hipStream_t stream) {
  const float* x = (const float*)d_in[0];
  const int* q4 = (const int*)d_in[1];
  const float* nrm = (const float*)d_in[2];
  const float* la = (const float*)d_in[3];
  const float* lb = (const float*)d_in[4];
  const float* lng = (const float*)d_in[5];
  const float* lnb = (const float*)d_in[6];

  short* Wb = (short*)d_ws;                             // 24 MB: 12 x [1024][1024] bf16
  short* buf0 = (short*)((char*)d_ws + (24u << 20));    // 8 MB
  short* buf1 = buf0 + (long)NB * CD;                   // 8 MB
  short* buf2 = (short*)d_out;                          // d_out lower 8 MB as bf16 scratch
  short* buf3 = buf2 + (long)NB * CD;                   // d_out upper 8 MB
  float* outf = (float*)d_out;

  prep_kernel<<<dim3(8192), dim3(256), 0, stream>>>(x, buf0, q4, nrm, la, lb, Wb);

  dim3 gg(256), bb(1024);
  auto Wl = [&](int l) { return Wb + ((long)l << 20); };

  // block 1 (input xb = buf0, resid buf0)
  qgemm<0><<<gg, bb, 0, stream>>>(buf0, Wl(0), nullptr, buf1);
  qgemm<0><<<gg, bb, 0, stream>>>(buf1, Wl(1), nullptr, buf2);
  qgemm<2><<<gg, bb, 0, stream>>>(buf2, Wl(2), buf0, buf3);
  ln_kernel<<<dim3(4096), dim3(256), 0, stream>>>(buf3, buf0, lng, lnb);
  // block 2 (input/resid buf0)
  qgemm<0><<<gg, bb, 0, stream>>>(buf0, Wl(3), nullptr, buf1);
  qgemm<0><<<gg, bb, 0, stream>>>(buf1, Wl(4), nullptr, buf2);
  qgemm<2><<<gg, bb, 0, stream>>>(buf2, Wl(5), buf0, buf3);
  // block 3 (input/resid buf3)
  qgemm<0><<<gg, bb, 0, stream>>>(buf3, Wl(6), nullptr, buf1);
  qgemm<0><<<gg, bb, 0, stream>>>(buf1, Wl(7), nullptr, buf2);
  qgemm<2><<<gg, bb, 0, stream>>>(buf2, Wl(8), buf3, buf0);
  ln_kernel<<<dim3(4096), dim3(256), 0, stream>>>(buf0, buf1, lng + CD, lnb + CD);
  // block 4 (input/resid buf1), final layer writes f32 to d_out
  qgemm<0><<<gg, bb, 0, stream>>>(buf1, Wl(9), nullptr, buf2);
  qgemm<0><<<gg, bb, 0, stream>>>(buf2, Wl(10), nullptr, buf0);
  qgemm<3><<<gg, bb, 0, stream>>>(buf0, Wl(11), buf1, (void*)outf);
}

// Round 9
// 297.710 us; speedup vs baseline: 1.0306x; 1.0306x over previous
//
#include <hip/hip_runtime.h>

#define CD 1024
#define NB 4096

typedef __attribute__((ext_vector_type(8))) short short8;
typedef __attribute__((ext_vector_type(4))) short short4v;
typedef __attribute__((ext_vector_type(4))) float f32x4;
typedef __attribute__((ext_vector_type(4))) int int4v;

typedef __attribute__((address_space(1))) const void gv_t;
typedef __attribute__((address_space(3))) void lv_t;
#define GLOAD16(g, l) __builtin_amdgcn_global_load_lds((gv_t*)(g), (lv_t*)(l), 16, 0, 0)
#define MF(a, b, c) __builtin_amdgcn_mfma_f32_16x16x32_bf16((a), (b), (c), 0, 0, 0)

__device__ __forceinline__ short f2bf(float f) {
  unsigned u = __float_as_uint(f);
  u = (u + 0x7FFFu + ((u >> 16) & 1u)) >> 16;
  return (short)u;
}
__device__ __forceinline__ float bf2f(short s) {
  return __uint_as_float(((unsigned)(unsigned short)s) << 16);
}

// ---- fused: x f32->bf16 (blocks 0..2047) + dequant12+LoRA-fold (blocks 2048..8191) ----
__global__ __launch_bounds__(256) void prep_kernel(const float* __restrict__ x,
                                                   short* __restrict__ xb,
                                                   const int* __restrict__ q4,
                                                   const float* __restrict__ nrm,
                                                   const float* __restrict__ la,
                                                   const float* __restrict__ lb,
                                                   short* __restrict__ Wb) {
  int bid = blockIdx.x;
  if (bid < 2048) {
    int i = (bid * 256 + threadIdx.x) * 8;
    f32x4 a = *(const f32x4*)(x + i);
    f32x4 b = *(const f32x4*)(x + i + 4);
    short8 o;
    o[0] = f2bf(a[0]); o[1] = f2bf(a[1]); o[2] = f2bf(a[2]); o[3] = f2bf(a[3]);
    o[4] = f2bf(b[0]); o[5] = f2bf(b[1]); o[6] = f2bf(b[2]); o[7] = f2bf(b[3]);
    *(short8*)(xb + i) = o;
    return;
  }
  int tidg = (bid - 2048) * 256 + threadIdx.x;
  int w0 = tidg * 4;
  int l = w0 >> 19;
  int wl = w0 & 524287;
  int g = wl >> 6;
  int j0 = wl & 63;
  int o = g >> 3;
  int kb = ((g & 7) << 7) + (j0 << 1);
  int4v q = *(const int4v*)(q4 + w0);
  float n = nrm[(l << 13) + g];
  float s = n * (2.0f / 15.0f);
  f32x4 B = *(const f32x4*)(lb + (((l << 10) + o) << 2));
  const float* A = la + (l << 12);
  float Ar[4][8];
#pragma unroll
  for (int r = 0; r < 4; ++r) {
    f32x4 u = *(const f32x4*)(A + r * CD + kb);
    f32x4 v = *(const f32x4*)(A + r * CD + kb + 4);
    Ar[r][0] = u[0]; Ar[r][1] = u[1]; Ar[r][2] = u[2]; Ar[r][3] = u[3];
    Ar[r][4] = v[0]; Ar[r][5] = v[1]; Ar[r][6] = v[2]; Ar[r][7] = v[3];
  }
  short8 outv;
#pragma unroll
  for (int p = 0; p < 8; ++p) {
    int qw = q[p >> 1];
    int nib = (qw >> ((p & 1) << 2)) & 15;
    float wv = (float)nib * s - n;
    wv += B[0] * Ar[0][p] + B[1] * Ar[1][p] + B[2] * Ar[2][p] + B[3] * Ar[3][p];
    outv[p] = f2bf(wv);
  }
  *(short8*)(Wb + (l << 20) + (o << 10) + kb) = outv;
}

// ---- GEMM: out[M,O] = Act[M,K] @ W[O,K]^T, bf16 in, f32 acc ----
// m201-style phased schedule ported to BM=BN=128, BK=64, 8 waves (64x32
// wave-tile). 3 LDS buffers, stage 2 tiles ahead, boundary vmcnt(4) (never 0
// mid-loop), raw s_barrier, 2 phases/K-tile {6 ds_read + 2 gload + lgkm(0) +
// setprio-wrapped 8 MFMA}. Grid 256 = 1 block/CU; XCD 4x8 patch map.
// EPI: 0 = relu->bf16, 2 = +resid->bf16, 3 = +resid->f32
template <int EPI>
__global__ __launch_bounds__(512) void qgemm(const short* __restrict__ Act,
                                             const short* __restrict__ W,
                                             const short* __restrict__ Res,
                                             void* __restrict__ Out) {
  __shared__ __align__(16) short ldsA[3][128 * 64];
  __shared__ __align__(16) short ldsB[3][128 * 64];
  const int tid = threadIdx.x;
  const int lane = tid & 63;
  const int wid = tid >> 6;
  const int wr = wid >> 2;                 // 0..1 : 64-row slice
  const int wc = wid & 3;                  // 0..3 : 32-col slice
  const int f = blockIdx.x;
  const int xcd = f & 7, c = f >> 3;
  const int m0 = (((xcd << 2) | (c & 3)) << 7);  // 32 M-tiles
  const int o0 = ((c >> 2) << 7);                // 8 O-tiles

  // staging sources (pre-swizzled ch ^= row&7; LDS dest linear):
  // per operand 1024 chunks of 16B; thread handles c = tid, tid+512.
  const short* asrc[2];
  const short* bsrc[2];
#pragma unroll
  for (int i = 0; i < 2; ++i) {
    int cc = tid + (i << 9);
    int row = cc >> 3;
    int ch = (cc & 7) ^ (row & 7);
    asrc[i] = Act + (long)(m0 + row) * CD + (ch << 3);
    bsrc[i] = W + (long)(o0 + row) * CD + (ch << 3);
  }

  f32x4 acc[4][2] = {};
  const int frow = lane & 15;
  const int fch = lane >> 4;               // 0..3
  const int fsw = lane & 7;

  // prologue: tiles 0,1 fully staged (order per tile: A0,A1,B0,B1)
#pragma unroll
  for (int pt = 0; pt < 2; ++pt) {
    const int koff = pt << 6;
    GLOAD16(asrc[0] + koff, &ldsA[pt][(tid) << 3]);
    GLOAD16(asrc[1] + koff, &ldsA[pt][(tid + 512) << 3]);
    GLOAD16(bsrc[0] + koff, &ldsB[pt][(tid) << 3]);
    GLOAD16(bsrc[1] + koff, &ldsB[pt][(tid + 512) << 3]);
  }

  int t3 = 0;                              // t % 3
  for (int t = 0; t < 16; ++t) {
    const short* La = ldsA[t3];
    const short* Lb = ldsB[t3];
    const int b2 = (t3 == 0) ? 2 : t3 - 1; // (t+2) % 3
    const int koff2 = (t + 2) << 6;
    // ---- tile boundary: my 4 oldest (tile t) retired; t+1's 4 stay in flight
    if (t < 15) asm volatile("s_waitcnt vmcnt(4)" ::: "memory");
    else        asm volatile("s_waitcnt vmcnt(0)" ::: "memory");
    __builtin_amdgcn_sched_barrier(0);
    __builtin_amdgcn_s_barrier();          // all waves: tile t landed everywhere
    __builtin_amdgcn_sched_barrier(0);
    // ================= PHASE 0 (kk = 0) =================
    {
      const int chsw = fch ^ fsw;
      short8 af0 = *(const short8*)(La + (((wr << 6) + 0  + frow) << 6) + (chsw << 3));
      short8 af1 = *(const short8*)(La + (((wr << 6) + 16 + frow) << 6) + (chsw << 3));
      short8 af2 = *(const short8*)(La + (((wr << 6) + 32 + frow) << 6) + (chsw << 3));
      short8 af3 = *(const short8*)(La + (((wr << 6) + 48 + frow) << 6) + (chsw << 3));
      short8 wf0 = *(const short8*)(Lb + (((wc << 5) + 0  + frow) << 6) + (chsw << 3));
      short8 wf1 = *(const short8*)(Lb + (((wc << 5) + 16 + frow) << 6) + (chsw << 3));
      if (t < 14) {                        // stage tile t+2: A chunks
        GLOAD16(asrc[0] + koff2, &ldsA[b2][(tid) << 3]);
        GLOAD16(asrc[1] + koff2, &ldsA[b2][(tid + 512) << 3]);
      }
      asm volatile("s_waitcnt lgkmcnt(0)" ::: "memory");
      __builtin_amdgcn_sched_barrier(0);
      __builtin_amdgcn_s_setprio(1);
      acc[0][0] = MF(wf0, af0, acc[0][0]); acc[0][1] = MF(wf1, af0, acc[0][1]);
      acc[1][0] = MF(wf0, af1, acc[1][0]); acc[1][1] = MF(wf1, af1, acc[1][1]);
      acc[2][0] = MF(wf0, af2, acc[2][0]); acc[2][1] = MF(wf1, af2, acc[2][1]);
      acc[3][0] = MF(wf0, af3, acc[3][0]); acc[3][1] = MF(wf1, af3, acc[3][1]);
      __builtin_amdgcn_s_setprio(0);
    }
    __builtin_amdgcn_s_barrier();
    __builtin_amdgcn_sched_barrier(0);
    // ================= PHASE 1 (kk = 1) =================
    {
      const int chsw = (4 + fch) ^ fsw;
      short8 af0 = *(const short8*)(La + (((wr << 6) + 0  + frow) << 6) + (chsw << 3));
      short8 af1 = *(const short8*)(La + (((wr << 6) + 16 + frow) << 6) + (chsw << 3));
      short8 af2 = *(const short8*)(La + (((wr << 6) + 32 + frow) << 6) + (chsw << 3));
      short8 af3 = *(const short8*)(La + (((wr << 6) + 48 + frow) << 6) + (chsw << 3));
      short8 wf0 = *(const short8*)(Lb + (((wc << 5) + 0  + frow) << 6) + (chsw << 3));
      short8 wf1 = *(const short8*)(Lb + (((wc << 5) + 16 + frow) << 6) + (chsw << 3));
      if (t < 14) {                        // stage tile t+2: B chunks
        GLOAD16(bsrc[0] + koff2, &ldsB[b2][(tid) << 3]);
        GLOAD16(bsrc[1] + koff2, &ldsB[b2][(tid + 512) << 3]);
      }
      asm volatile("s_waitcnt lgkmcnt(0)" ::: "memory");
      __builtin_amdgcn_sched_barrier(0);
      __builtin_amdgcn_s_setprio(1);
      acc[0][0] = MF(wf0, af0, acc[0][0]); acc[0][1] = MF(wf1, af0, acc[0][1]);
      acc[1][0] = MF(wf0, af1, acc[1][0]); acc[1][1] = MF(wf1, af1, acc[1][1]);
      acc[2][0] = MF(wf0, af2, acc[2][0]); acc[2][1] = MF(wf1, af2, acc[2][1]);
      acc[3][0] = MF(wf0, af3, acc[3][0]); acc[3][1] = MF(wf1, af3, acc[3][1]);
      __builtin_amdgcn_s_setprio(0);
    }
    t3 = (t3 == 2) ? 0 : t3 + 1;
  }

  // epilogue (swapped operands): lane&15 = M-row, (lane>>4)*4+reg = out-col
  const int orow = m0 + (wr << 6) + frow;
  const int ocol = o0 + (wc << 5) + (fch << 2);
#pragma unroll
  for (int m = 0; m < 4; ++m) {
#pragma unroll
    for (int n = 0; n < 2; ++n) {
      long row = orow + (m << 4);
      int col = ocol + (n << 4);
      f32x4 v = acc[m][n];
      if (EPI == 0) {
        short4v ov;
        ov[0] = f2bf(fmaxf(v[0], 0.0f));
        ov[1] = f2bf(fmaxf(v[1], 0.0f));
        ov[2] = f2bf(fmaxf(v[2], 0.0f));
        ov[3] = f2bf(fmaxf(v[3], 0.0f));
        *(short4v*)((short*)Out + row * CD + col) = ov;
      } else if (EPI == 2) {
        short4v rv = *(const short4v*)(Res + row * CD + col);
        short4v ov;
        ov[0] = f2bf(v[0] + bf2f(rv[0]));
        ov[1] = f2bf(v[1] + bf2f(rv[1]));
        ov[2] = f2bf(v[2] + bf2f(rv[2]));
        ov[3] = f2bf(v[3] + bf2f(rv[3]));
        *(short4v*)((short*)Out + row * CD + col) = ov;
      } else {
        short4v rv = *(const short4v*)(Res + row * CD + col);
        f32x4 ov;
        ov[0] = v[0] + bf2f(rv[0]);
        ov[1] = v[1] + bf2f(rv[1]);
        ov[2] = v[2] + bf2f(rv[2]);
        ov[3] = v[3] + bf2f(rv[3]);
        *(f32x4*)((float*)Out + row * CD + col) = ov;
      }
    }
  }
}

// ---- LayerNorm over rows of 1024 bf16 ----
__global__ __launch_bounds__(256) void ln_kernel(const short* __restrict__ in,
                                                 short* __restrict__ out,
                                                 const float* __restrict__ g,
                                                 const float* __restrict__ b) {
  __shared__ float rs_[4], rq_[4];
  int row = blockIdx.x, tid = threadIdx.x;
  int k = tid * 4;
  short4v v = *(const short4v*)(in + (long)row * CD + k);
  float f0 = bf2f(v[0]), f1 = bf2f(v[1]), f2 = bf2f(v[2]), f3 = bf2f(v[3]);
  float s = f0 + f1 + f2 + f3;
  float q = f0 * f0 + f1 * f1 + f2 * f2 + f3 * f3;
#pragma unroll
  for (int off = 1; off < 64; off <<= 1) {
    s += __shfl_xor(s, off);
    q += __shfl_xor(q, off);
  }
  if ((tid & 63) == 0) { rs_[tid >> 6] = s; rq_[tid >> 6] = q; }
  __syncthreads();
  s = rs_[0] + rs_[1] + rs_[2] + rs_[3];
  q = rq_[0] + rq_[1] + rq_[2] + rq_[3];
  float mu = s * (1.0f / 1024.0f);
  float var = q * (1.0f / 1024.0f) - mu * mu;
  float rstd = rsqrtf(var + 1e-5f);
  short4v o;
  o[0] = f2bf((f0 - mu) * rstd * g[k] + b[k]);
  o[1] = f2bf((f1 - mu) * rstd * g[k + 1] + b[k + 1]);
  o[2] = f2bf((f2 - mu) * rstd * g[k + 2] + b[k + 2]);
  o[3] = f2bf((f3 - mu) * rstd * g[k + 3] + b[k + 3]);
  *(short4v*)(out + (long)row * CD + k) = o;
}

extern "C" void kernel_launch(void* const* d_in, const int* in_sizes, int n_in,
                              void* d_out, int out_size, void* d_ws, size_t ws_size,
                              hipStream_t stream) {
  const float* x = (const float*)d_in[0];
  const int* q4 = (const int*)d_in[1];
  const float* nrm = (const float*)d_in[2];
  const float* la = (const float*)d_in[3];
  const float* lb = (const float*)d_in[4];
  const float* lng = (const float*)d_in[5];
  const float* lnb = (const float*)d_in[6];

  short* Wb = (short*)d_ws;                             // 24 MB: 12 x [1024][1024] bf16
  short* buf0 = (short*)((char*)d_ws + (24u << 20));    // 8 MB
  short* buf1 = buf0 + (long)NB * CD;                   // 8 MB
  short* buf2 = (short*)d_out;                          // d_out lower 8 MB as bf16 scratch
  short* buf3 = buf2 + (long)NB * CD;                   // d_out upper 8 MB
  float* outf = (float*)d_out;

  prep_kernel<<<dim3(8192), dim3(256), 0, stream>>>(x, buf0, q4, nrm, la, lb, Wb);

  dim3 gg(256), bb(512);
  auto Wl = [&](int l) { return Wb + ((long)l << 20); };

  // block 1 (input xb = buf0, resid buf0)
  qgemm<0><<<gg, bb, 0, stream>>>(buf0, Wl(0), nullptr, buf1);
  qgemm<0><<<gg, bb, 0, stream>>>(buf1, Wl(1), nullptr, buf2);
  qgemm<2><<<gg, bb, 0, stream>>>(buf2, Wl(2), buf0, buf3);
  ln_kernel<<<dim3(4096), dim3(256), 0, stream>>>(buf3, buf0, lng, lnb);
  // block 2 (input/resid buf0)
  qgemm<0><<<gg, bb, 0, stream>>>(buf0, Wl(3), nullptr, buf1);
  qgemm<0><<<gg, bb, 0, stream>>>(buf1, Wl(4), nullptr, buf2);
  qgemm<2><<<gg, bb, 0, stream>>>(buf2, Wl(5), buf0, buf3);
  // block 3 (input/resid buf3)
  qgemm<0><<<gg, bb, 0, stream>>>(buf3, Wl(6), nullptr, buf1);
  qgemm<0><<<gg, bb, 0, stream>>>(buf1, Wl(7), nullptr, buf2);
  qgemm<2><<<gg, bb, 0, stream>>>(buf2, Wl(8), buf3, buf0);
  ln_kernel<<<dim3(4096), dim3(256), 0, stream>>>(buf0, buf1, lng + CD, lnb + CD);
  // block 4 (input/resid buf1), final layer writes f32 to d_out
  qgemm<0><<<gg, bb, 0, stream>>>(buf1, Wl(9), nullptr, buf2);
  qgemm<0><<<gg, bb, 0, stream>>>(buf2, Wl(10), nullptr, buf0);
  qgemm<3><<<gg, bb, 0, stream>>>(buf0, Wl(11), buf1, (void*)outf);
}